// Round 6
// baseline (685.323 us; speedup 1.0000x reference)
//
#include <hip/hip_runtime.h>

#define BATCH 16384
#define CH 512
#define EPSBN 1e-5f

typedef __attribute__((ext_vector_type(8))) short short8;
typedef __attribute__((ext_vector_type(4))) float f32x4;
typedef __attribute__((ext_vector_type(4))) unsigned short ushort4v;

#define GLOAD16(gp, lp) __builtin_amdgcn_global_load_lds( \
    (const __attribute__((address_space(1))) void*)(gp),  \
    (__attribute__((address_space(3))) void*)(lp), 16, 0, 0)

// edge table: etab[node-1][j] = edge id; bct[e] = B-weight counter
__constant__ int d_etab[6][6] = {
  {0,0,0,0,0,0},
  {1,6,0,0,0,0},
  {2,7,11,0,0,0},
  {3,8,12,15,0,0},
  {4,9,13,16,18,0},
  {5,10,14,17,19,20}};
__constant__ int d_bct[21] = {0,0,0,0,0,0, 0,1,3,6,10, 2,4,7,11, 5,8,12, 9,13, 14};

static __device__ __forceinline__ long woff(int e){
  return (e < 6) ? (long)e*524288 : 3145728L + (long)d_bct[e]*262144;
}

static __device__ __forceinline__ unsigned short f2b(float f){
  union { float f; unsigned u; } v; v.f = f;
  unsigned r = v.u + 0x7fffu + ((v.u >> 16) & 1u);
  return (unsigned short)(r >> 16);
}
static __device__ __forceinline__ float b2f(unsigned short u){
  union { unsigned u; float f; } v; v.u = ((unsigned)u) << 16; return v.f;
}

__global__ void k_sentinel(float* out){ out[0] = 1.0e6f; }

// ---------------- index / wscale ----------------
__global__ void k_index(const float* __restrict__ ap, const float* __restrict__ gum,
                        int* __restrict__ idx, float* __restrict__ wsc){
  int e = threadIdx.x;
  if (e >= 21) return;
  const float* a = ap + e*9;
  const float* g = gum + e*9;
  float m = a[0];
  for (int o=1;o<9;o++) m = fmaxf(m, a[o]);
  float s = 0.f;
  for (int o=0;o<9;o++) s += expf(a[o]-m);
  float lse = m + logf(s);
  float lg[9]; float lm = -1e30f;
  for (int o=0;o<9;o++){ lg[o] = (a[o]-lse+g[o]) / 10.0f; lm = fmaxf(lm, lg[o]); }
  float ss = 0.f;
  for (int o=0;o<9;o++) ss += expf(lg[o]-lm);
  int bi = 0; float bp = -1.f;
  for (int o=0;o<9;o++){
    float p = expf(lg[o]-lm)/ss;
    if (p > bp){ bp = p; bi = o; }
  }
  idx[e] = bi;
  wsc[e] = (1.0f - bp) + bp;
}

// ---------------- fp32 -> bf16 (vector4, grid-stride) ----------------
__global__ void k_f2b4(const float* __restrict__ in, unsigned short* __restrict__ outp, long n4){
  long stride = (long)gridDim.x*blockDim.x;
  for (long i = (long)blockIdx.x*blockDim.x + threadIdx.x; i < n4; i += stride){
    const float4 v = ((const float4*)in)[i];
    ushort4v o;
    o[0] = f2b(v.x); o[1] = f2b(v.y); o[2] = f2b(v.z); o[3] = f2b(v.w);
    ((ushort4v*)outp)[i] = o;
  }
}

// ---------------- all selected weights -> bf16 slots ----------------
__global__ void k_wconv_all(const int* __restrict__ idxp,
                            const float* __restrict__ dwA, const float* __restrict__ pwA,
                            const float* __restrict__ gwA, const float* __restrict__ dwB,
                            const float* __restrict__ gwB,
                            unsigned short* __restrict__ Wball){
  int e = blockIdx.x >> 7;          // 21 edges x 128 blocks
  int blk = blockIdx.x & 127;
  int id = idxp[e];
  const float* src; long n;
  if (e < 6){
    int a = e;
    if (id >= 2 && id <= 4){ n = 524288; src = dwA + ((long)a*3 + (id-2))*n; }
    else if (id < 2)       { n = 524288; src = pwA + ((long)a*2 + id)*n; }
    else if (id <= 7)      { n = 131072; src = gwA + ((long)a*3 + (id-5))*131072; }
    else return;
  } else {
    int b = d_bct[e];
    if (id >= 2 && id <= 4)     { n = 262144; src = dwB + ((long)b*3 + (id-2))*n; }
    else if (id >= 5 && id <= 7){ n = 65536;  src = gwB + ((long)b*3 + (id-5))*65536; }
    else return;
  }
  unsigned short* dst = Wball + woff(e);
  long n4 = n >> 2;
  long stride = 128*256;
  for (long i = (long)blk*256 + threadIdx.x; i < n4; i += stride){
    const float4 v = ((const float4*)src)[i];
    ushort4v o;
    o[0] = f2b(v.x); o[1] = f2b(v.y); o[2] = f2b(v.z); o[3] = f2b(v.w);
    ((ushort4v*)dst)[i] = o;
  }
}

// ---------------- pool-A pre-GEMM: tmp = bf16(relu(x) @ pw^T) ----------------
// 128x128 tile, BK=32, dbuf prefetch, swizzled LDS, acc[4][4] (m97 geometry)
__global__ __launch_bounds__(256) void k_gemm_pool(
    int node, const unsigned short* __restrict__ xb,
    const unsigned short* __restrict__ Wball, unsigned short* __restrict__ tmp,
    const int* __restrict__ idxp)
{
  int e = node - 1;
  int id = idxp[e];
  if (id >= 2) return;

  int bid = blockIdx.x;
  int lg = (bid & 7) * 64 + (bid >> 3);      // 512 blocks, bijective
  int rowTile = lg >> 2, colTile = lg & 3;
  int row0 = rowTile * 128, col0 = colTile * 128;

  int t = threadIdx.x;
  int lane = t & 63, wave = t >> 6;
  int wm = wave >> 1, wn = wave & 1;
  int l16 = lane & 15, lq = lane >> 4;

  __shared__ unsigned short LDS[16384];   // A dbuf [0/4096], B dbuf [8192/12288]

  int ra = t >> 2;
  int ca = (((t & 3) ^ ((ra >> 1) & 3)) << 3);
  int aoff[4], boff[4];
  #pragma unroll
  for (int m=0;m<4;m++){ int R = wm*64 + m*16 + l16; aoff[m] = R*32 + ((lq ^ ((R>>1)&3))<<3); }
  #pragma unroll
  for (int n=0;n<4;n++){ int C = wn*64 + n*16 + l16; boff[n] = C*32 + ((lq ^ ((C>>1)&3))<<3); }

  const unsigned short* W = Wball + (long)e*524288 + (long)col0*1024;
  const unsigned short* gA0 = xb + (long)(row0 + ra)*1024 + ca;
  const unsigned short* gA1 = gA0 + (long)64*1024;
  const unsigned short* gB0 = W  + (long)ra*1024 + ca;
  const unsigned short* gB1 = gB0 + (long)64*1024;

  f32x4 acc[4][4];
  #pragma unroll
  for (int m=0;m<4;m++)
    #pragma unroll
    for (int n=0;n<4;n++) acc[m][n] = (f32x4){0,0,0,0};

  GLOAD16(gA0, &LDS[t*8]);
  GLOAD16(gA1, &LDS[2048 + t*8]);
  GLOAD16(gB0, &LDS[8192 + t*8]);
  GLOAD16(gB1, &LDS[8192 + 2048 + t*8]);
  __syncthreads();

  int buf = 0;
  for (int kt = 0; kt < 32; ++kt){
    int nb = buf ^ 1;
    if (kt+1 < 32){
      long kk = (long)(kt+1)*32;
      GLOAD16(gA0 + kk, &LDS[nb*4096 + t*8]);
      GLOAD16(gA1 + kk, &LDS[nb*4096 + 2048 + t*8]);
      GLOAD16(gB0 + kk, &LDS[8192 + nb*4096 + t*8]);
      GLOAD16(gB1 + kk, &LDS[8192 + nb*4096 + 2048 + t*8]);
    }
    const unsigned short* pA = &LDS[buf*4096];
    const unsigned short* pB = &LDS[8192 + buf*4096];
    short8 a[4], b[4];
    #pragma unroll
    for (int m=0;m<4;m++){
      a[m] = *(const short8*)(pA + aoff[m]);
      #pragma unroll
      for (int q=0;q<8;q++) a[m][q] = (a[m][q] < (short)0) ? (short)0 : a[m][q];
    }
    #pragma unroll
    for (int n=0;n<4;n++) b[n] = *(const short8*)(pB + boff[n]);
    #pragma unroll
    for (int m=0;m<4;m++)
      #pragma unroll
      for (int n=0;n<4;n++)
        acc[m][n] = __builtin_amdgcn_mfma_f32_16x16x32_bf16(a[m], b[n], acc[m][n], 0,0,0);
    __syncthreads();
    buf = nb;
  }

  #pragma unroll
  for (int n=0;n<4;n++){
    int cn = col0 + wn*64 + n*16 + l16;
    #pragma unroll
    for (int m=0;m<4;m++)
      #pragma unroll
      for (int r=0;r<4;r++){
        int row = row0 + wm*64 + m*16 + lq*4 + r;
        tmp[(long)row*CH + cn] = f2b(acc[m][n][r]);
      }
  }
}

// ---------------- node stats pass1 ----------------
__global__ __launch_bounds__(512) void k_stats_node(
    int node, const unsigned short* __restrict__ tmp,
    const unsigned short* __restrict__ sb0, const unsigned short* __restrict__ sb1,
    const unsigned short* __restrict__ sb2, const unsigned short* __restrict__ sb3,
    const unsigned short* __restrict__ sb4,
    float* __restrict__ part, const int* __restrict__ idxp)
{
  int c = threadIdx.x;
  for (int jj = 0; jj < node; ++jj){
    int e = d_etab[node-1][jj];
    if (idxp[e] >= 2) continue;
    const unsigned short* S;
    switch(jj){ case 0: S=tmp; break; case 1: S=sb0; break; case 2: S=sb1; break;
                case 3: S=sb2; break; case 4: S=sb3; break; default: S=sb4; }
    const unsigned short* p = S + (long)blockIdx.x*128*CH + c;
    float s = 0.f, q = 0.f;
    for (int r = 0; r < 128; r++){ float v = b2f(p[(long)r*CH]); s += v; q += v*v; }
    long o = (((long)jj*128 + blockIdx.x)*CH + c)*2;
    part[o] = s; part[o+1] = q;
  }
}

// ---------------- node stats pass2 ----------------
__global__ __launch_bounds__(512) void k_stats2_node(
    int node, const float* __restrict__ part,
    float* __restrict__ alphaAll, float* __restrict__ mvalAll,
    const int* __restrict__ idxp)
{
  int c = threadIdx.x;
  for (int jj = 0; jj < node; ++jj){
    int e = d_etab[node-1][jj];
    int id = idxp[e];
    if (id >= 2) continue;
    float s = 0.f, q = 0.f;
    for (int b = 0; b < 128; b++){
      long o = (((long)jj*128 + b)*CH + c)*2;
      s += part[o]; q += part[o+1];
    }
    float m = s * (1.f/16384.f);
    float v = q * (1.f/16384.f) - m*m;
    v = fmaxf(v, 0.f);
    float al;
    if (jj == 0){
      float s1 = rsqrtf(v + EPSBN);
      float vz = v / (v + EPSBN);
      al = (id==0) ? (s1 * (1.f/9.f) * rsqrtf(vz*(1.f/81.f) + EPSBN))
                   : (s1 * rsqrtf(vz + EPSBN));
    } else {
      al = (id==0) ? ((1.f/9.f) * rsqrtf(v*(1.f/81.f) + EPSBN))
                   : rsqrtf(v + EPSBN);
    }
    alphaAll[(long)e*CH + c] = al;
    mvalAll[(long)e*CH + c] = m;
  }
}

// ---------------- fused per-node kernel: 128x128 tile, acc[4][4] ----------------
__global__ __launch_bounds__(256) void k_fused(
    int node,
    const unsigned short* __restrict__ xb,
    const unsigned short* __restrict__ sb0, const unsigned short* __restrict__ sb1,
    const unsigned short* __restrict__ sb2, const unsigned short* __restrict__ sb3,
    const unsigned short* __restrict__ sb4,
    unsigned short* __restrict__ sbout, float* __restrict__ outf,
    const unsigned short* __restrict__ tmp, const unsigned short* __restrict__ Wball,
    const float* __restrict__ dbA, const float* __restrict__ gbA,
    const float* __restrict__ dbB, const float* __restrict__ gbB,
    const float* __restrict__ alphaAll, const float* __restrict__ mvalAll,
    const int* __restrict__ idxp, const float* __restrict__ wscp)
{
  int bid = blockIdx.x;
  int lg = (bid & 7) * 64 + (bid >> 3);      // 512 blocks, bijective
  int rowTile = lg >> 2, colTile = lg & 3;
  int row0 = rowTile * 128, col0 = colTile * 128;

  int t = threadIdx.x;
  int lane = t & 63, wave = t >> 6;
  int wm = wave >> 1, wn = wave & 1;
  int l16 = lane & 15, lq = lane >> 4;

  __shared__ unsigned short LDS[16384];   // A dbuf [0/4096], B dbuf [8192/12288]

  int ra = t >> 2;
  int ca = (((t & 3) ^ ((ra >> 1) & 3)) << 3);
  int aoff[4], boff[4];
  #pragma unroll
  for (int m=0;m<4;m++){ int R = wm*64 + m*16 + l16; aoff[m] = R*32 + ((lq ^ ((R>>1)&3))<<3); }
  #pragma unroll
  for (int n=0;n<4;n++){ int C = wn*64 + n*16 + l16; boff[n] = C*32 + ((lq ^ ((C>>1)&3))<<3); }

  f32x4 facc[4][4];
  #pragma unroll
  for (int m=0;m<4;m++)
    #pragma unroll
    for (int n=0;n<4;n++) facc[m][n] = (f32x4){0,0,0,0};

  for (int jj = 0; jj < node; ++jj){
    int e = d_etab[node-1][jj];
    int id = idxp[e];
    if (id == 8) continue;
    float we = wscp[e];

    const unsigned short* st;
    switch(jj){ case 0: st=xb; break; case 1: st=sb0; break; case 2: st=sb1; break;
                case 3: st=sb2; break; case 4: st=sb3; break; default: st=sb4; }

    if (id < 2){
      // pool: facc += we*(S-m)*alpha
      const unsigned short* S = (jj==0) ? tmp : st;
      const float* al = alphaAll + (long)e*CH;
      const float* mv = mvalAll + (long)e*CH;
      #pragma unroll
      for (int n=0;n<4;n++){
        int cn = col0 + wn*64 + n*16 + l16;
        float a_n = al[cn], m_n = mv[cn];
        #pragma unroll
        for (int m=0;m<4;m++){
          int rowb = row0 + wm*64 + m*16 + lq*4;
          #pragma unroll
          for (int r=0;r<4;r++)
            facc[m][n][r] += we * (b2f(S[(long)(rowb+r)*CH + cn]) - m_n) * a_n;
        }
      }
      continue;
    }

    // GEMM edge (dense or group); BN=128 == one group when grp
    bool grp = (id >= 5);
    int cin = (jj==0) ? 1024 : 512;
    int K = grp ? (cin >> 2) : cin;
    int act = grp ? id - 5 : id - 2;
    const unsigned short* Abase = st + (grp ? (long)colTile*K : 0);
    const unsigned short* Wbase = Wball + woff(e) + (long)col0*K;
    const float* bias;
    if (jj == 0) bias = (grp ? gbA : dbA) + ((long)e*3 + act)*CH;
    else         bias = (grp ? gbB : dbB) + ((long)d_bct[e]*3 + act)*CH;

    const unsigned short* gA0 = Abase + (long)(row0 + ra)*cin + ca;
    const unsigned short* gA1 = gA0 + (long)64*cin;
    const unsigned short* gB0 = Wbase + (long)ra*K + ca;
    const unsigned short* gB1 = gB0 + (long)64*K;

    f32x4 acc[4][4];
    #pragma unroll
    for (int m=0;m<4;m++)
      #pragma unroll
      for (int n=0;n<4;n++) acc[m][n] = (f32x4){0,0,0,0};

    int nk = K >> 5;
    GLOAD16(gA0, &LDS[t*8]);
    GLOAD16(gA1, &LDS[2048 + t*8]);
    GLOAD16(gB0, &LDS[8192 + t*8]);
    GLOAD16(gB1, &LDS[8192 + 2048 + t*8]);
    __syncthreads();

    int buf = 0;
    for (int kt = 0; kt < nk; ++kt){
      int nb = buf ^ 1;
      if (kt+1 < nk){
        long kk = (long)(kt+1)*32;
        GLOAD16(gA0 + kk, &LDS[nb*4096 + t*8]);
        GLOAD16(gA1 + kk, &LDS[nb*4096 + 2048 + t*8]);
        GLOAD16(gB0 + kk, &LDS[8192 + nb*4096 + t*8]);
        GLOAD16(gB1 + kk, &LDS[8192 + nb*4096 + 2048 + t*8]);
      }
      const unsigned short* pA = &LDS[buf*4096];
      const unsigned short* pB = &LDS[8192 + buf*4096];
      short8 a[4], b[4];
      #pragma unroll
      for (int m=0;m<4;m++) a[m] = *(const short8*)(pA + aoff[m]);
      #pragma unroll
      for (int n=0;n<4;n++) b[n] = *(const short8*)(pB + boff[n]);
      #pragma unroll
      for (int m=0;m<4;m++)
        #pragma unroll
        for (int n=0;n<4;n++)
          acc[m][n] = __builtin_amdgcn_mfma_f32_16x16x32_bf16(a[m], b[n], acc[m][n], 0,0,0);
      __syncthreads();
      buf = nb;
    }

    #pragma unroll
    for (int n=0;n<4;n++){
      int cn = col0 + wn*64 + n*16 + l16;
      float bv = bias[cn];
      #pragma unroll
      for (int m=0;m<4;m++)
        #pragma unroll
        for (int r=0;r<4;r++){
          float v = acc[m][n][r] + bv;
          v = (act==0) ? fmaxf(v, 0.f) : (act==1) ? (1.f/(1.f+expf(-v))) : tanhf(v);
          facc[m][n][r] += we * v;
        }
    }
  }

  // epilogue: write state (bf16) or final output (fp32)
  #pragma unroll
  for (int n=0;n<4;n++){
    int cn = col0 + wn*64 + n*16 + l16;
    #pragma unroll
    for (int m=0;m<4;m++){
      int rowb = row0 + wm*64 + m*16 + lq*4;
      #pragma unroll
      for (int r=0;r<4;r++){
        long off = (long)(rowb+r)*CH + cn;
        if (node == 6) outf[off] = facc[m][n][r];
        else           sbout[off] = f2b(facc[m][n][r]);
      }
    }
  }
}

extern "C" void kernel_launch(void* const* d_in, const int* in_sizes, int n_in,
                              void* d_out, int out_size, void* d_ws, size_t ws_size,
                              hipStream_t stream)
{
  const float* x   = (const float*)d_in[0];
  const float* ap  = (const float*)d_in[1];
  const float* gum = (const float*)d_in[2];
  const float* dwA = (const float*)d_in[3];
  const float* dbA = (const float*)d_in[4];
  const float* gwA = (const float*)d_in[5];
  const float* gbA = (const float*)d_in[6];
  const float* pwA = (const float*)d_in[7];
  const float* dwB = (const float*)d_in[8];
  const float* dbB = (const float*)d_in[9];
  const float* gwB = (const float*)d_in[10];
  const float* gbB = (const float*)d_in[11];
  float* out = (float*)d_out;

  char* ws = (char*)d_ws;
  size_t cur = 0;
  auto alloc = [&](size_t bytes)->void*{
    size_t o = cur; cur += (bytes + 255) & ~(size_t)255; return (void*)(ws + o);
  };
  int*   idx      = (int*)  alloc(21*sizeof(int));
  float* wsc      = (float*)alloc(21*sizeof(float));
  float* alphaAll = (float*)alloc((size_t)21*CH*sizeof(float));
  float* mvalAll  = (float*)alloc((size_t)21*CH*sizeof(float));
  float* part     = (float*)alloc((size_t)6*128*CH*2*sizeof(float));
  unsigned short* Wball = (unsigned short*)alloc((size_t)7077888*sizeof(unsigned short));
  unsigned short* tmp   = (unsigned short*)alloc((size_t)BATCH*CH*sizeof(unsigned short));
  unsigned short* xb    = (unsigned short*)alloc((size_t)BATCH*1024*sizeof(unsigned short));
  unsigned short* sb[5];
  for (int i=0;i<5;i++)
    sb[i] = (unsigned short*)alloc((size_t)BATCH*CH*sizeof(unsigned short));

  if (cur > ws_size){
    hipLaunchKernelGGL(k_sentinel, dim3(1), dim3(1), 0, stream, out);
    return;
  }

  hipLaunchKernelGGL(k_f2b4, dim3(2048), dim3(256), 0, stream, x, xb, (long)BATCH*1024/4);
  hipLaunchKernelGGL(k_index, dim3(1), dim3(32), 0, stream, ap, gum, idx, wsc);
  hipLaunchKernelGGL(k_wconv_all, dim3(21*128), dim3(256), 0, stream,
                     idx, dwA, pwA, gwA, dwB, gwB, Wball);

  for (int node = 1; node <= 6; node++){
    hipLaunchKernelGGL(k_gemm_pool, dim3(512), dim3(256), 0, stream,
                       node, xb, Wball, tmp, idx);
    hipLaunchKernelGGL(k_stats_node, dim3(128), dim3(512), 0, stream,
                       node, tmp, sb[0], sb[1], sb[2], sb[3], sb[4], part, idx);
    hipLaunchKernelGGL(k_stats2_node, dim3(1), dim3(512), 0, stream,
                       node, part, alphaAll, mvalAll, idx);
    hipLaunchKernelGGL(k_fused, dim3(512), dim3(256), 0, stream,
                       node, xb, sb[0], sb[1], sb[2], sb[3], sb[4],
                       (node < 6) ? sb[node-1] : sb[0], out,
                       tmp, Wball, dbA, gbA, dbB, gbB,
                       alphaAll, mvalAll, idx, wsc);
  }
}

// Round 7
// 428.742 us; speedup vs baseline: 1.5985x; 1.5985x over previous
//
#include <hip/hip_runtime.h>

#define BATCH 16384
#define CH 512
#define EPSBN 1e-5f

typedef __attribute__((ext_vector_type(8))) short short8;
typedef __attribute__((ext_vector_type(4))) float f32x4;
typedef __attribute__((ext_vector_type(4))) unsigned short ushort4v;

#define GLOAD16(gp, lp) __builtin_amdgcn_global_load_lds( \
    (const __attribute__((address_space(1))) void*)(gp),  \
    (__attribute__((address_space(3))) void*)(lp), 16, 0, 0)

// edge table: etab[node-1][j] = edge id; bct[e] = B-weight counter
__constant__ int d_etab[6][6] = {
  {0,0,0,0,0,0},
  {1,6,0,0,0,0},
  {2,7,11,0,0,0},
  {3,8,12,15,0,0},
  {4,9,13,16,18,0},
  {5,10,14,17,19,20}};
__constant__ int d_bct[21] = {0,0,0,0,0,0, 0,1,3,6,10, 2,4,7,11, 5,8,12, 9,13, 14};

static __device__ __forceinline__ long woff(int e){
  return (e < 6) ? (long)e*524288 : 3145728L + (long)d_bct[e]*262144;
}

static __device__ __forceinline__ unsigned short f2b(float f){
  union { float f; unsigned u; } v; v.f = f;
  unsigned r = v.u + 0x7fffu + ((v.u >> 16) & 1u);
  return (unsigned short)(r >> 16);
}
static __device__ __forceinline__ float b2f(unsigned short u){
  union { unsigned u; float f; } v; v.u = ((unsigned)u) << 16; return v.f;
}
static __device__ __forceinline__ float actf(int act, float v){
  if (act == 0) return fmaxf(v, 0.f);
  if (act == 1) return 1.f/(1.f + __expf(-v));
  float e = __expf(2.f*v);                    // tanh = 1 - 2/(e^{2v}+1)
  return 1.f - 2.f/(e + 1.f);
}

__global__ void k_sentinel(float* out){ out[0] = 1.0e6f; }

// ---------------- index / wscale ----------------
__global__ void k_index(const float* __restrict__ ap, const float* __restrict__ gum,
                        int* __restrict__ idx, float* __restrict__ wsc){
  int e = threadIdx.x;
  if (e >= 21) return;
  const float* a = ap + e*9;
  const float* g = gum + e*9;
  float m = a[0];
  for (int o=1;o<9;o++) m = fmaxf(m, a[o]);
  float s = 0.f;
  for (int o=0;o<9;o++) s += expf(a[o]-m);
  float lse = m + logf(s);
  float lg[9]; float lm = -1e30f;
  for (int o=0;o<9;o++){ lg[o] = (a[o]-lse+g[o]) / 10.0f; lm = fmaxf(lm, lg[o]); }
  float ss = 0.f;
  for (int o=0;o<9;o++) ss += expf(lg[o]-lm);
  int bi = 0; float bp = -1.f;
  for (int o=0;o<9;o++){
    float p = expf(lg[o]-lm)/ss;
    if (p > bp){ bp = p; bi = o; }
  }
  idx[e] = bi;
  wsc[e] = (1.0f - bp) + bp;
}

// ---------------- fp32 -> bf16 (vector4, grid-stride) ----------------
__global__ void k_f2b4(const float* __restrict__ in, unsigned short* __restrict__ outp, long n4){
  long stride = (long)gridDim.x*blockDim.x;
  for (long i = (long)blockIdx.x*blockDim.x + threadIdx.x; i < n4; i += stride){
    const float4 v = ((const float4*)in)[i];
    ushort4v o;
    o[0] = f2b(v.x); o[1] = f2b(v.y); o[2] = f2b(v.z); o[3] = f2b(v.w);
    ((ushort4v*)outp)[i] = o;
  }
}

// ---------------- all selected weights -> bf16 slots ----------------
__global__ void k_wconv_all(const int* __restrict__ idxp,
                            const float* __restrict__ dwA, const float* __restrict__ pwA,
                            const float* __restrict__ gwA, const float* __restrict__ dwB,
                            const float* __restrict__ gwB,
                            unsigned short* __restrict__ Wball){
  int e = blockIdx.x >> 7;          // 21 edges x 128 blocks
  int blk = blockIdx.x & 127;
  int id = idxp[e];
  const float* src; long n;
  if (e < 6){
    int a = e;
    if (id >= 2 && id <= 4){ n = 524288; src = dwA + ((long)a*3 + (id-2))*n; }
    else if (id < 2)       { n = 524288; src = pwA + ((long)a*2 + id)*n; }
    else if (id <= 7)      { n = 131072; src = gwA + ((long)a*3 + (id-5))*131072; }
    else return;
  } else {
    int b = d_bct[e];
    if (id >= 2 && id <= 4)     { n = 262144; src = dwB + ((long)b*3 + (id-2))*n; }
    else if (id >= 5 && id <= 7){ n = 65536;  src = gwB + ((long)b*3 + (id-5))*65536; }
    else return;
  }
  unsigned short* dst = Wball + woff(e);
  long n4 = n >> 2;
  long stride = 128*256;
  for (long i = (long)blk*256 + threadIdx.x; i < n4; i += stride){
    const float4 v = ((const float4*)src)[i];
    ushort4v o;
    o[0] = f2b(v.x); o[1] = f2b(v.y); o[2] = f2b(v.z); o[3] = f2b(v.w);
    ((ushort4v*)dst)[i] = o;
  }
}

// ---------------- pool-A pre-GEMM: tmp = bf16(relu(x) @ pw^T) ----------------
// 128x128 tile, 8 waves (2Mx4N), BK=32, dbuf prefetch, swizzled LDS
__global__ __launch_bounds__(512, 4) void k_gemm_pool(
    int node, const unsigned short* __restrict__ xb,
    const unsigned short* __restrict__ Wball, unsigned short* __restrict__ tmp,
    const int* __restrict__ idxp)
{
  int e = node - 1;
  int id = idxp[e];
  if (id >= 2) return;

  int bid = blockIdx.x;
  int lg = (bid & 7) * 64 + (bid >> 3);      // 512 blocks, bijective
  int rowTile = lg >> 2, colTile = lg & 3;
  int row0 = rowTile * 128, col0 = colTile * 128;

  int t = threadIdx.x;
  int lane = t & 63, wave = t >> 6;
  int wm = wave >> 2, wn = wave & 3;
  int l16 = lane & 15, lq = lane >> 4;

  __shared__ unsigned short LDS[16384];   // A dbuf [0/4096], B dbuf [8192/12288]

  int ra = t >> 2;                         // 0..127
  int ca = (((t & 3) ^ ((ra >> 1) & 3)) << 3);
  int aoff[4], boff[2];
  #pragma unroll
  for (int m=0;m<4;m++){ int R = wm*64 + m*16 + l16; aoff[m] = R*32 + ((lq ^ ((R>>1)&3))<<3); }
  #pragma unroll
  for (int n=0;n<2;n++){ int C = wn*32 + n*16 + l16; boff[n] = C*32 + ((lq ^ ((C>>1)&3))<<3); }

  const unsigned short* W = Wball + (long)e*524288 + (long)col0*1024;
  const unsigned short* gA = xb + (long)(row0 + ra)*1024 + ca;
  const unsigned short* gB = W  + (long)ra*1024 + ca;

  f32x4 acc[4][2];
  #pragma unroll
  for (int m=0;m<4;m++){ acc[m][0]=(f32x4){0,0,0,0}; acc[m][1]=(f32x4){0,0,0,0}; }

  GLOAD16(gA, &LDS[t*8]);
  GLOAD16(gB, &LDS[8192 + t*8]);
  __syncthreads();

  int buf = 0;
  for (int kt = 0; kt < 32; ++kt){
    int nb = buf ^ 1;
    if (kt+1 < 32){
      long kk = (long)(kt+1)*32;
      GLOAD16(gA + kk, &LDS[nb*4096 + t*8]);
      GLOAD16(gB + kk, &LDS[8192 + nb*4096 + t*8]);
    }
    const unsigned short* pA = &LDS[buf*4096];
    const unsigned short* pB = &LDS[8192 + buf*4096];
    short8 a[4], b[2];
    #pragma unroll
    for (int m=0;m<4;m++){
      a[m] = *(const short8*)(pA + aoff[m]);
      #pragma unroll
      for (int q=0;q<8;q++) a[m][q] = (a[m][q] < (short)0) ? (short)0 : a[m][q];
    }
    #pragma unroll
    for (int n=0;n<2;n++) b[n] = *(const short8*)(pB + boff[n]);
    #pragma unroll
    for (int m=0;m<4;m++)
      #pragma unroll
      for (int n=0;n<2;n++)
        acc[m][n] = __builtin_amdgcn_mfma_f32_16x16x32_bf16(a[m], b[n], acc[m][n], 0,0,0);
    __syncthreads();
    buf = nb;
  }

  #pragma unroll
  for (int n=0;n<2;n++){
    int cn = col0 + wn*32 + n*16 + l16;
    #pragma unroll
    for (int m=0;m<4;m++)
      #pragma unroll
      for (int r=0;r<4;r++){
        int row = row0 + wm*64 + m*16 + lq*4 + r;
        tmp[(long)row*CH + cn] = f2b(acc[m][n][r]);
      }
  }
}

// ---------------- node stats pass1 ----------------
__global__ __launch_bounds__(512) void k_stats_node(
    int node, const unsigned short* __restrict__ tmp,
    const unsigned short* __restrict__ sb0, const unsigned short* __restrict__ sb1,
    const unsigned short* __restrict__ sb2, const unsigned short* __restrict__ sb3,
    const unsigned short* __restrict__ sb4,
    float* __restrict__ part, const int* __restrict__ idxp)
{
  int c = threadIdx.x;
  for (int jj = 0; jj < node; ++jj){
    int e = d_etab[node-1][jj];
    if (idxp[e] >= 2) continue;
    const unsigned short* S;
    switch(jj){ case 0: S=tmp; break; case 1: S=sb0; break; case 2: S=sb1; break;
                case 3: S=sb2; break; case 4: S=sb3; break; default: S=sb4; }
    const unsigned short* p = S + (long)blockIdx.x*128*CH + c;
    float s = 0.f, q = 0.f;
    for (int r = 0; r < 128; r++){ float v = b2f(p[(long)r*CH]); s += v; q += v*v; }
    long o = (((long)jj*128 + blockIdx.x)*CH + c)*2;
    part[o] = s; part[o+1] = q;
  }
}

// ---------------- node stats pass2 ----------------
__global__ __launch_bounds__(512) void k_stats2_node(
    int node, const float* __restrict__ part,
    float* __restrict__ alphaAll, float* __restrict__ mvalAll,
    const int* __restrict__ idxp)
{
  int c = threadIdx.x;
  for (int jj = 0; jj < node; ++jj){
    int e = d_etab[node-1][jj];
    int id = idxp[e];
    if (id >= 2) continue;
    float s = 0.f, q = 0.f;
    for (int b = 0; b < 128; b++){
      long o = (((long)jj*128 + b)*CH + c)*2;
      s += part[o]; q += part[o+1];
    }
    float m = s * (1.f/16384.f);
    float v = q * (1.f/16384.f) - m*m;
    v = fmaxf(v, 0.f);
    float al;
    if (jj == 0){
      float s1 = rsqrtf(v + EPSBN);
      float vz = v / (v + EPSBN);
      al = (id==0) ? (s1 * (1.f/9.f) * rsqrtf(vz*(1.f/81.f) + EPSBN))
                   : (s1 * rsqrtf(vz + EPSBN));
    } else {
      al = (id==0) ? ((1.f/9.f) * rsqrtf(v*(1.f/81.f) + EPSBN))
                   : rsqrtf(v + EPSBN);
    }
    alphaAll[(long)e*CH + c] = al;
    mvalAll[(long)e*CH + c] = m;
  }
}

// ---------------- fused per-node kernel: 128x128 tile, 8 waves, acc[4][2] ----------------
__global__ __launch_bounds__(512, 4) void k_fused(
    int node,
    const unsigned short* __restrict__ xb,
    const unsigned short* __restrict__ sb0, const unsigned short* __restrict__ sb1,
    const unsigned short* __restrict__ sb2, const unsigned short* __restrict__ sb3,
    const unsigned short* __restrict__ sb4,
    unsigned short* __restrict__ sbout, float* __restrict__ outf,
    const unsigned short* __restrict__ tmp, const unsigned short* __restrict__ Wball,
    const float* __restrict__ dbA, const float* __restrict__ gbA,
    const float* __restrict__ dbB, const float* __restrict__ gbB,
    const float* __restrict__ alphaAll, const float* __restrict__ mvalAll,
    const int* __restrict__ idxp, const float* __restrict__ wscp)
{
  int bid = blockIdx.x;
  int lg = (bid & 7) * 64 + (bid >> 3);      // 512 blocks, bijective
  int rowTile = lg >> 2, colTile = lg & 3;
  int row0 = rowTile * 128, col0 = colTile * 128;

  int t = threadIdx.x;
  int lane = t & 63, wave = t >> 6;
  int wm = wave >> 2, wn = wave & 3;
  int l16 = lane & 15, lq = lane >> 4;

  __shared__ unsigned short LDS[16384];   // A dbuf [0/4096], B dbuf [8192/12288]

  int ra = t >> 2;
  int ca = (((t & 3) ^ ((ra >> 1) & 3)) << 3);
  int aoff[4], boff[2];
  #pragma unroll
  for (int m=0;m<4;m++){ int R = wm*64 + m*16 + l16; aoff[m] = R*32 + ((lq ^ ((R>>1)&3))<<3); }
  #pragma unroll
  for (int n=0;n<2;n++){ int C = wn*32 + n*16 + l16; boff[n] = C*32 + ((lq ^ ((C>>1)&3))<<3); }

  f32x4 facc[4][2];
  #pragma unroll
  for (int m=0;m<4;m++){ facc[m][0]=(f32x4){0,0,0,0}; facc[m][1]=(f32x4){0,0,0,0}; }

  for (int jj = 0; jj < node; ++jj){
    int e = d_etab[node-1][jj];
    int id = idxp[e];
    if (id == 8) continue;
    float we = wscp[e];

    const unsigned short* st;
    switch(jj){ case 0: st=xb; break; case 1: st=sb0; break; case 2: st=sb1; break;
                case 3: st=sb2; break; case 4: st=sb3; break; default: st=sb4; }

    if (id < 2){
      // pool: facc += we*(S-m)*alpha
      const unsigned short* S = (jj==0) ? tmp : st;
      const float* al = alphaAll + (long)e*CH;
      const float* mv = mvalAll + (long)e*CH;
      #pragma unroll
      for (int n=0;n<2;n++){
        int cn = col0 + wn*32 + n*16 + l16;
        float a_n = al[cn], m_n = mv[cn];
        #pragma unroll
        for (int m=0;m<4;m++){
          int rowb = row0 + wm*64 + m*16 + lq*4;
          #pragma unroll
          for (int r=0;r<4;r++)
            facc[m][n][r] += we * (b2f(S[(long)(rowb+r)*CH + cn]) - m_n) * a_n;
        }
      }
      continue;
    }

    // GEMM edge (dense or group); BN=128 == one group when grp
    bool grp = (id >= 5);
    int cin = (jj==0) ? 1024 : 512;
    int K = grp ? (cin >> 2) : cin;
    int act = grp ? id - 5 : id - 2;
    const unsigned short* Abase = st + (grp ? (long)colTile*K : 0);
    const unsigned short* Wbase = Wball + woff(e) + (long)col0*K;
    const float* bias;
    if (jj == 0) bias = (grp ? gbA : dbA) + ((long)e*3 + act)*CH;
    else         bias = (grp ? gbB : dbB) + ((long)d_bct[e]*3 + act)*CH;

    const unsigned short* gA = Abase + (long)(row0 + ra)*cin + ca;
    const unsigned short* gB = Wbase + (long)ra*K + ca;

    f32x4 acc[4][2];
    #pragma unroll
    for (int m=0;m<4;m++){ acc[m][0]=(f32x4){0,0,0,0}; acc[m][1]=(f32x4){0,0,0,0}; }

    int nk = K >> 5;
    GLOAD16(gA, &LDS[t*8]);
    GLOAD16(gB, &LDS[8192 + t*8]);
    __syncthreads();

    int buf = 0;
    for (int kt = 0; kt < nk; ++kt){
      int nb = buf ^ 1;
      if (kt+1 < nk){
        long kk = (long)(kt+1)*32;
        GLOAD16(gA + kk, &LDS[nb*4096 + t*8]);
        GLOAD16(gB + kk, &LDS[8192 + nb*4096 + t*8]);
      }
      const unsigned short* pA = &LDS[buf*4096];
      const unsigned short* pB = &LDS[8192 + buf*4096];
      short8 a[4], b[2];
      #pragma unroll
      for (int m=0;m<4;m++) a[m] = *(const short8*)(pA + aoff[m]);
      #pragma unroll
      for (int n=0;n<2;n++) b[n] = *(const short8*)(pB + boff[n]);
      #pragma unroll
      for (int m=0;m<4;m++)
        #pragma unroll
        for (int n=0;n<2;n++)
          acc[m][n] = __builtin_amdgcn_mfma_f32_16x16x32_bf16(a[m], b[n], acc[m][n], 0,0,0);
      __syncthreads();
      buf = nb;
    }

    #pragma unroll
    for (int n=0;n<2;n++){
      int cn = col0 + wn*32 + n*16 + l16;
      float bv = bias[cn];
      #pragma unroll
      for (int m=0;m<4;m++)
        #pragma unroll
        for (int r=0;r<4;r++)
          facc[m][n][r] += we * actf(act, acc[m][n][r] + bv);
    }
  }

  // epilogue: write state (bf16) or final output (fp32)
  #pragma unroll
  for (int n=0;n<2;n++){
    int cn = col0 + wn*32 + n*16 + l16;
    #pragma unroll
    for (int m=0;m<4;m++){
      int rowb = row0 + wm*64 + m*16 + lq*4;
      #pragma unroll
      for (int r=0;r<4;r++){
        long off = (long)(rowb+r)*CH + cn;
        if (node == 6) outf[off] = facc[m][n][r];
        else           sbout[off] = f2b(facc[m][n][r]);
      }
    }
  }
}

extern "C" void kernel_launch(void* const* d_in, const int* in_sizes, int n_in,
                              void* d_out, int out_size, void* d_ws, size_t ws_size,
                              hipStream_t stream)
{
  const float* x   = (const float*)d_in[0];
  const float* ap  = (const float*)d_in[1];
  const float* gum = (const float*)d_in[2];
  const float* dwA = (const float*)d_in[3];
  const float* dbA = (const float*)d_in[4];
  const float* gwA = (const float*)d_in[5];
  const float* gbA = (const float*)d_in[6];
  const float* pwA = (const float*)d_in[7];
  const float* dwB = (const float*)d_in[8];
  const float* dbB = (const float*)d_in[9];
  const float* gwB = (const float*)d_in[10];
  const float* gbB = (const float*)d_in[11];
  float* out = (float*)d_out;

  char* ws = (char*)d_ws;
  size_t cur = 0;
  auto alloc = [&](size_t bytes)->void*{
    size_t o = cur; cur += (bytes + 255) & ~(size_t)255; return (void*)(ws + o);
  };
  int*   idx      = (int*)  alloc(21*sizeof(int));
  float* wsc      = (float*)alloc(21*sizeof(float));
  float* alphaAll = (float*)alloc((size_t)21*CH*sizeof(float));
  float* mvalAll  = (float*)alloc((size_t)21*CH*sizeof(float));
  float* part     = (float*)alloc((size_t)6*128*CH*2*sizeof(float));
  unsigned short* Wball = (unsigned short*)alloc((size_t)7077888*sizeof(unsigned short));
  unsigned short* tmp   = (unsigned short*)alloc((size_t)BATCH*CH*sizeof(unsigned short));
  unsigned short* xb    = (unsigned short*)alloc((size_t)BATCH*1024*sizeof(unsigned short));
  unsigned short* sb[5];
  for (int i=0;i<5;i++)
    sb[i] = (unsigned short*)alloc((size_t)BATCH*CH*sizeof(unsigned short));

  if (cur > ws_size){
    hipLaunchKernelGGL(k_sentinel, dim3(1), dim3(1), 0, stream, out);
    return;
  }

  hipLaunchKernelGGL(k_f2b4, dim3(2048), dim3(256), 0, stream, x, xb, (long)BATCH*1024/4);
  hipLaunchKernelGGL(k_index, dim3(1), dim3(32), 0, stream, ap, gum, idx, wsc);
  hipLaunchKernelGGL(k_wconv_all, dim3(21*128), dim3(256), 0, stream,
                     idx, dwA, pwA, gwA, dwB, gwB, Wball);

  for (int node = 1; node <= 6; node++){
    hipLaunchKernelGGL(k_gemm_pool, dim3(512), dim3(512), 0, stream,
                       node, xb, Wball, tmp, idx);
    hipLaunchKernelGGL(k_stats_node, dim3(128), dim3(512), 0, stream,
                       node, tmp, sb[0], sb[1], sb[2], sb[3], sb[4], part, idx);
    hipLaunchKernelGGL(k_stats2_node, dim3(1), dim3(512), 0, stream,
                       node, part, alphaAll, mvalAll, idx);
    hipLaunchKernelGGL(k_fused, dim3(512), dim3(512), 0, stream,
                       node, xb, sb[0], sb[1], sb[2], sb[3], sb[4],
                       (node < 6) ? sb[node-1] : sb[0], out,
                       tmp, Wball, dbA, gbA, dbB, gbB,
                       alphaAll, mvalAll, idx, wsc);
  }
}

// Round 8
// 420.000 us; speedup vs baseline: 1.6317x; 1.0208x over previous
//
#include <hip/hip_runtime.h>

#define BATCH 16384
#define CH 512
#define EPSBN 1e-5f

typedef __attribute__((ext_vector_type(8))) short short8;
typedef __attribute__((ext_vector_type(4))) float f32x4;
typedef __attribute__((ext_vector_type(4))) unsigned short ushort4v;

#define GLOAD16(gp, lp) __builtin_amdgcn_global_load_lds( \
    (const __attribute__((address_space(1))) void*)(gp),  \
    (__attribute__((address_space(3))) void*)(lp), 16, 0, 0)

// edge table: etab[node-1][j] = edge id; bct[e] = B-weight counter
__constant__ int d_etab[6][6] = {
  {0,0,0,0,0,0},
  {1,6,0,0,0,0},
  {2,7,11,0,0,0},
  {3,8,12,15,0,0},
  {4,9,13,16,18,0},
  {5,10,14,17,19,20}};
__constant__ int d_bct[21] = {0,0,0,0,0,0, 0,1,3,6,10, 2,4,7,11, 5,8,12, 9,13, 14};

static __device__ __forceinline__ long woff(int e){
  return (e < 6) ? (long)e*524288 : 3145728L + (long)d_bct[e]*262144;
}

static __device__ __forceinline__ unsigned short f2b(float f){
  union { float f; unsigned u; } v; v.f = f;
  unsigned r = v.u + 0x7fffu + ((v.u >> 16) & 1u);
  return (unsigned short)(r >> 16);
}
static __device__ __forceinline__ float b2f(unsigned short u){
  union { unsigned u; float f; } v; v.u = ((unsigned)u) << 16; return v.f;
}
static __device__ __forceinline__ float actf(int act, float v){
  if (act == 0) return fmaxf(v, 0.f);
  if (act == 1) return 1.f/(1.f + __expf(-v));
  float e = __expf(2.f*v);                    // tanh = 1 - 2/(e^{2v}+1)
  return 1.f - 2.f/(e + 1.f);
}

__global__ void k_sentinel(float* out){ out[0] = 1.0e6f; }

// ---------------- index / wscale ----------------
__global__ void k_index(const float* __restrict__ ap, const float* __restrict__ gum,
                        int* __restrict__ idx, float* __restrict__ wsc){
  int e = threadIdx.x;
  if (e >= 21) return;
  const float* a = ap + e*9;
  const float* g = gum + e*9;
  float m = a[0];
  for (int o=1;o<9;o++) m = fmaxf(m, a[o]);
  float s = 0.f;
  for (int o=0;o<9;o++) s += expf(a[o]-m);
  float lse = m + logf(s);
  float lg[9]; float lm = -1e30f;
  for (int o=0;o<9;o++){ lg[o] = (a[o]-lse+g[o]) / 10.0f; lm = fmaxf(lm, lg[o]); }
  float ss = 0.f;
  for (int o=0;o<9;o++) ss += expf(lg[o]-lm);
  int bi = 0; float bp = -1.f;
  for (int o=0;o<9;o++){
    float p = expf(lg[o]-lm)/ss;
    if (p > bp){ bp = p; bi = o; }
  }
  idx[e] = bi;
  wsc[e] = (1.0f - bp) + bp;
}

// ---------------- fp32 -> bf16 (vector4, grid-stride) ----------------
__global__ void k_f2b4(const float* __restrict__ in, unsigned short* __restrict__ outp, long n4){
  long stride = (long)gridDim.x*blockDim.x;
  for (long i = (long)blockIdx.x*blockDim.x + threadIdx.x; i < n4; i += stride){
    const float4 v = ((const float4*)in)[i];
    ushort4v o;
    o[0] = f2b(v.x); o[1] = f2b(v.y); o[2] = f2b(v.z); o[3] = f2b(v.w);
    ((ushort4v*)outp)[i] = o;
  }
}

// ---------------- all selected weights -> bf16 slots ----------------
__global__ void k_wconv_all(const int* __restrict__ idxp,
                            const float* __restrict__ dwA, const float* __restrict__ pwA,
                            const float* __restrict__ gwA, const float* __restrict__ dwB,
                            const float* __restrict__ gwB,
                            unsigned short* __restrict__ Wball){
  int e = blockIdx.x >> 7;          // 21 edges x 128 blocks
  int blk = blockIdx.x & 127;
  int id = idxp[e];
  const float* src; long n;
  if (e < 6){
    int a = e;
    if (id >= 2 && id <= 4){ n = 524288; src = dwA + ((long)a*3 + (id-2))*n; }
    else if (id < 2)       { n = 524288; src = pwA + ((long)a*2 + id)*n; }
    else if (id <= 7)      { n = 131072; src = gwA + ((long)a*3 + (id-5))*131072; }
    else return;
  } else {
    int b = d_bct[e];
    if (id >= 2 && id <= 4)     { n = 262144; src = dwB + ((long)b*3 + (id-2))*n; }
    else if (id >= 5 && id <= 7){ n = 65536;  src = gwB + ((long)b*3 + (id-5))*65536; }
    else return;
  }
  unsigned short* dst = Wball + woff(e);
  long n4 = n >> 2;
  long stride = 128*256;
  for (long i = (long)blk*256 + threadIdx.x; i < n4; i += stride){
    const float4 v = ((const float4*)src)[i];
    ushort4v o;
    o[0] = f2b(v.x); o[1] = f2b(v.y); o[2] = f2b(v.z); o[3] = f2b(v.w);
    ((ushort4v*)dst)[i] = o;
  }
}

// ---------------- pool-A pre-GEMM: tmp = bf16(relu(x) @ pw^T) ----------------
// 128x128 tile, 8 waves, BK=32, triple-buffer depth-2 counted-vmcnt pipeline
__global__ __launch_bounds__(512, 4) void k_gemm_pool(
    int node, const unsigned short* __restrict__ xb,
    const unsigned short* __restrict__ Wball, unsigned short* __restrict__ tmp,
    const int* __restrict__ idxp)
{
  int e = node - 1;
  int id = idxp[e];
  if (id >= 2) return;

  int bid = blockIdx.x;
  int lg = (bid & 7) * 64 + (bid >> 3);      // 512 blocks, bijective
  int rowTile = lg >> 2, colTile = lg & 3;
  int row0 = rowTile * 128, col0 = colTile * 128;

  int t = threadIdx.x;
  int lane = t & 63, wave = t >> 6;
  int wm = wave >> 2, wn = wave & 3;
  int l16 = lane & 15, lq = lane >> 4;

  __shared__ unsigned short LDS[24576];   // A buf x3 @0/4096/8192, B buf x3 @12288/16384/20480

  int ra = t >> 2;                         // 0..127
  int ca = (((t & 3) ^ ((ra >> 1) & 3)) << 3);
  int aoff[4], boff[2];
  #pragma unroll
  for (int m=0;m<4;m++){ int R = wm*64 + m*16 + l16; aoff[m] = R*32 + ((lq ^ ((R>>1)&3))<<3); }
  #pragma unroll
  for (int n=0;n<2;n++){ int C = wn*32 + n*16 + l16; boff[n] = C*32 + ((lq ^ ((C>>1)&3))<<3); }

  const unsigned short* W = Wball + (long)e*524288 + (long)col0*1024;
  const unsigned short* gA = xb + (long)(row0 + ra)*1024 + ca;
  const unsigned short* gB = W  + (long)ra*1024 + ca;

  f32x4 acc[4][2];
  #pragma unroll
  for (int m=0;m<4;m++){ acc[m][0]=(f32x4){0,0,0,0}; acc[m][1]=(f32x4){0,0,0,0}; }

  auto STAGE = [&](int tile, int bsel){
    long kk = (long)tile*32;
    GLOAD16(gA + kk, &LDS[bsel*4096 + t*8]);
    GLOAD16(gB + kk, &LDS[12288 + bsel*4096 + t*8]);
  };

  const int nk = 32;
  STAGE(0, 0);
  STAGE(1, 1);
  int cb = 0;
  for (int kt = 0; kt < nk; ++kt){
    if (kt+1 < nk) { asm volatile("s_waitcnt vmcnt(2)" ::: "memory"); }
    else           { asm volatile("s_waitcnt vmcnt(0)" ::: "memory"); }
    __builtin_amdgcn_s_barrier();
    if (kt+2 < nk) STAGE(kt+2, (cb >= 1) ? cb-1 : cb+2);
    const unsigned short* pA = &LDS[cb*4096];
    const unsigned short* pB = &LDS[12288 + cb*4096];
    short8 a[4], b[2];
    #pragma unroll
    for (int m=0;m<4;m++){
      a[m] = *(const short8*)(pA + aoff[m]);
      #pragma unroll
      for (int q=0;q<8;q++) a[m][q] = (a[m][q] < (short)0) ? (short)0 : a[m][q];
    }
    #pragma unroll
    for (int n=0;n<2;n++) b[n] = *(const short8*)(pB + boff[n]);
    #pragma unroll
    for (int m=0;m<4;m++)
      #pragma unroll
      for (int n=0;n<2;n++)
        acc[m][n] = __builtin_amdgcn_mfma_f32_16x16x32_bf16(a[m], b[n], acc[m][n], 0,0,0);
    cb = (cb+1 == 3) ? 0 : cb+1;
  }

  #pragma unroll
  for (int n=0;n<2;n++){
    int cn = col0 + wn*32 + n*16 + l16;
    #pragma unroll
    for (int m=0;m<4;m++)
      #pragma unroll
      for (int r=0;r<4;r++){
        int row = row0 + wm*64 + m*16 + lq*4 + r;
        tmp[(long)row*CH + cn] = f2b(acc[m][n][r]);
      }
  }
}

// ---------------- node stats pass1 ----------------
__global__ __launch_bounds__(512) void k_stats_node(
    int node, const unsigned short* __restrict__ tmp,
    const unsigned short* __restrict__ sb0, const unsigned short* __restrict__ sb1,
    const unsigned short* __restrict__ sb2, const unsigned short* __restrict__ sb3,
    const unsigned short* __restrict__ sb4,
    float* __restrict__ part, const int* __restrict__ idxp)
{
  int c = threadIdx.x;
  for (int jj = 0; jj < node; ++jj){
    int e = d_etab[node-1][jj];
    if (idxp[e] >= 2) continue;
    const unsigned short* S;
    switch(jj){ case 0: S=tmp; break; case 1: S=sb0; break; case 2: S=sb1; break;
                case 3: S=sb2; break; case 4: S=sb3; break; default: S=sb4; }
    const unsigned short* p = S + (long)blockIdx.x*128*CH + c;
    float s = 0.f, q = 0.f;
    for (int r = 0; r < 128; r++){ float v = b2f(p[(long)r*CH]); s += v; q += v*v; }
    long o = (((long)jj*128 + blockIdx.x)*CH + c)*2;
    part[o] = s; part[o+1] = q;
  }
}

// ---------------- node stats pass2 ----------------
__global__ __launch_bounds__(512) void k_stats2_node(
    int node, const float* __restrict__ part,
    float* __restrict__ alphaAll, float* __restrict__ mvalAll,
    const int* __restrict__ idxp)
{
  int c = threadIdx.x;
  for (int jj = 0; jj < node; ++jj){
    int e = d_etab[node-1][jj];
    int id = idxp[e];
    if (id >= 2) continue;
    float s = 0.f, q = 0.f;
    for (int b = 0; b < 128; b++){
      long o = (((long)jj*128 + b)*CH + c)*2;
      s += part[o]; q += part[o+1];
    }
    float m = s * (1.f/16384.f);
    float v = q * (1.f/16384.f) - m*m;
    v = fmaxf(v, 0.f);
    float al;
    if (jj == 0){
      float s1 = rsqrtf(v + EPSBN);
      float vz = v / (v + EPSBN);
      al = (id==0) ? (s1 * (1.f/9.f) * rsqrtf(vz*(1.f/81.f) + EPSBN))
                   : (s1 * rsqrtf(vz + EPSBN));
    } else {
      al = (id==0) ? ((1.f/9.f) * rsqrtf(v*(1.f/81.f) + EPSBN))
                   : rsqrtf(v + EPSBN);
    }
    alphaAll[(long)e*CH + c] = al;
    mvalAll[(long)e*CH + c] = m;
  }
}

// ---------------- fused per-node kernel: 128x128, 8 waves, counted-vmcnt pipeline ----------------
__global__ __launch_bounds__(512, 4) void k_fused(
    int node,
    const unsigned short* __restrict__ xb,
    const unsigned short* __restrict__ sb0, const unsigned short* __restrict__ sb1,
    const unsigned short* __restrict__ sb2, const unsigned short* __restrict__ sb3,
    const unsigned short* __restrict__ sb4,
    unsigned short* __restrict__ sbout, float* __restrict__ outf,
    const unsigned short* __restrict__ tmp, const unsigned short* __restrict__ Wball,
    const float* __restrict__ dbA, const float* __restrict__ gbA,
    const float* __restrict__ dbB, const float* __restrict__ gbB,
    const float* __restrict__ alphaAll, const float* __restrict__ mvalAll,
    const int* __restrict__ idxp, const float* __restrict__ wscp)
{
  int bid = blockIdx.x;
  int lg = (bid & 7) * 64 + (bid >> 3);      // 512 blocks, bijective
  int rowTile = lg >> 2, colTile = lg & 3;
  int row0 = rowTile * 128, col0 = colTile * 128;

  int t = threadIdx.x;
  int lane = t & 63, wave = t >> 6;
  int wm = wave >> 2, wn = wave & 3;
  int l16 = lane & 15, lq = lane >> 4;

  __shared__ unsigned short LDS[24576];   // A buf x3, B buf x3

  int ra = t >> 2;
  int ca = (((t & 3) ^ ((ra >> 1) & 3)) << 3);
  int aoff[4], boff[2];
  #pragma unroll
  for (int m=0;m<4;m++){ int R = wm*64 + m*16 + l16; aoff[m] = R*32 + ((lq ^ ((R>>1)&3))<<3); }
  #pragma unroll
  for (int n=0;n<2;n++){ int C = wn*32 + n*16 + l16; boff[n] = C*32 + ((lq ^ ((C>>1)&3))<<3); }

  f32x4 facc[4][2];
  #pragma unroll
  for (int m=0;m<4;m++){ facc[m][0]=(f32x4){0,0,0,0}; facc[m][1]=(f32x4){0,0,0,0}; }

  for (int jj = 0; jj < node; ++jj){
    int e = d_etab[node-1][jj];
    int id = idxp[e];
    if (id == 8) continue;
    float we = wscp[e];

    const unsigned short* st;
    switch(jj){ case 0: st=xb; break; case 1: st=sb0; break; case 2: st=sb1; break;
                case 3: st=sb2; break; case 4: st=sb3; break; default: st=sb4; }

    if (id < 2){
      // pool: facc += we*(S-m)*alpha
      const unsigned short* S = (jj==0) ? tmp : st;
      const float* al = alphaAll + (long)e*CH;
      const float* mv = mvalAll + (long)e*CH;
      #pragma unroll
      for (int n=0;n<2;n++){
        int cn = col0 + wn*32 + n*16 + l16;
        float a_n = al[cn], m_n = mv[cn];
        #pragma unroll
        for (int m=0;m<4;m++){
          int rowb = row0 + wm*64 + m*16 + lq*4;
          #pragma unroll
          for (int r=0;r<4;r++)
            facc[m][n][r] += we * (b2f(S[(long)(rowb+r)*CH + cn]) - m_n) * a_n;
        }
      }
      continue;
    }

    // GEMM edge (dense or group); BN=128 == one group when grp
    bool grp = (id >= 5);
    int cin = (jj==0) ? 1024 : 512;
    int K = grp ? (cin >> 2) : cin;
    int act = grp ? id - 5 : id - 2;
    const unsigned short* Abase = st + (grp ? (long)colTile*K : 0);
    const unsigned short* Wbase = Wball + woff(e) + (long)col0*K;
    const float* bias;
    if (jj == 0) bias = (grp ? gbA : dbA) + ((long)e*3 + act)*CH;
    else         bias = (grp ? gbB : dbB) + ((long)d_bct[e]*3 + act)*CH;

    const unsigned short* gA = Abase + (long)(row0 + ra)*cin + ca;
    const unsigned short* gB = Wbase + (long)ra*K + ca;

    f32x4 acc[4][2];
    #pragma unroll
    for (int m=0;m<4;m++){ acc[m][0]=(f32x4){0,0,0,0}; acc[m][1]=(f32x4){0,0,0,0}; }

    auto STAGE = [&](int tile, int bsel){
      long kk = (long)tile*32;
      GLOAD16(gA + kk, &LDS[bsel*4096 + t*8]);
      GLOAD16(gB + kk, &LDS[12288 + bsel*4096 + t*8]);
    };

    int nk = K >> 5;
    __builtin_amdgcn_s_barrier();   // prior edge's LDS readers are done
    STAGE(0, 0);
    STAGE(1, 1);
    int cb = 0;
    for (int kt = 0; kt < nk; ++kt){
      if (kt+1 < nk) { asm volatile("s_waitcnt vmcnt(2)" ::: "memory"); }
      else           { asm volatile("s_waitcnt vmcnt(0)" ::: "memory"); }
      __builtin_amdgcn_s_barrier();
      if (kt+2 < nk) STAGE(kt+2, (cb >= 1) ? cb-1 : cb+2);
      const unsigned short* pA = &LDS[cb*4096];
      const unsigned short* pB = &LDS[12288 + cb*4096];
      short8 a[4], b[2];
      #pragma unroll
      for (int m=0;m<4;m++) a[m] = *(const short8*)(pA + aoff[m]);
      #pragma unroll
      for (int n=0;n<2;n++) b[n] = *(const short8*)(pB + boff[n]);
      #pragma unroll
      for (int m=0;m<4;m++)
        #pragma unroll
        for (int n=0;n<2;n++)
          acc[m][n] = __builtin_amdgcn_mfma_f32_16x16x32_bf16(a[m], b[n], acc[m][n], 0,0,0);
      cb = (cb+1 == 3) ? 0 : cb+1;
    }

    #pragma unroll
    for (int n=0;n<2;n++){
      int cn = col0 + wn*32 + n*16 + l16;
      float bv = bias[cn];
      #pragma unroll
      for (int m=0;m<4;m++)
        #pragma unroll
        for (int r=0;r<4;r++)
          facc[m][n][r] += we * actf(act, acc[m][n][r] + bv);
    }
  }

  // epilogue: write state (bf16) or final output (fp32)
  #pragma unroll
  for (int n=0;n<2;n++){
    int cn = col0 + wn*32 + n*16 + l16;
    #pragma unroll
    for (int m=0;m<4;m++){
      int rowb = row0 + wm*64 + m*16 + lq*4;
      #pragma unroll
      for (int r=0;r<4;r++){
        long off = (long)(rowb+r)*CH + cn;
        if (node == 6) outf[off] = facc[m][n][r];
        else           sbout[off] = f2b(facc[m][n][r]);
      }
    }
  }
}

extern "C" void kernel_launch(void* const* d_in, const int* in_sizes, int n_in,
                              void* d_out, int out_size, void* d_ws, size_t ws_size,
                              hipStream_t stream)
{
  const float* x   = (const float*)d_in[0];
  const float* ap  = (const float*)d_in[1];
  const float* gum = (const float*)d_in[2];
  const float* dwA = (const float*)d_in[3];
  const float* dbA = (const float*)d_in[4];
  const float* gwA = (const float*)d_in[5];
  const float* gbA = (const float*)d_in[6];
  const float* pwA = (const float*)d_in[7];
  const float* dwB = (const float*)d_in[8];
  const float* dbB = (const float*)d_in[9];
  const float* gwB = (const float*)d_in[10];
  const float* gbB = (const float*)d_in[11];
  float* out = (float*)d_out;

  char* ws = (char*)d_ws;
  size_t cur = 0;
  auto alloc = [&](size_t bytes)->void*{
    size_t o = cur; cur += (bytes + 255) & ~(size_t)255; return (void*)(ws + o);
  };
  int*   idx      = (int*)  alloc(21*sizeof(int));
  float* wsc      = (float*)alloc(21*sizeof(float));
  float* alphaAll = (float*)alloc((size_t)21*CH*sizeof(float));
  float* mvalAll  = (float*)alloc((size_t)21*CH*sizeof(float));
  float* part     = (float*)alloc((size_t)6*128*CH*2*sizeof(float));
  unsigned short* Wball = (unsigned short*)alloc((size_t)7077888*sizeof(unsigned short));
  unsigned short* tmp   = (unsigned short*)alloc((size_t)BATCH*CH*sizeof(unsigned short));
  unsigned short* xb    = (unsigned short*)alloc((size_t)BATCH*1024*sizeof(unsigned short));
  unsigned short* sb[5];
  for (int i=0;i<5;i++)
    sb[i] = (unsigned short*)alloc((size_t)BATCH*CH*sizeof(unsigned short));

  if (cur > ws_size){
    hipLaunchKernelGGL(k_sentinel, dim3(1), dim3(1), 0, stream, out);
    return;
  }

  hipLaunchKernelGGL(k_f2b4, dim3(2048), dim3(256), 0, stream, x, xb, (long)BATCH*1024/4);
  hipLaunchKernelGGL(k_index, dim3(1), dim3(32), 0, stream, ap, gum, idx, wsc);
  hipLaunchKernelGGL(k_wconv_all, dim3(21*128), dim3(256), 0, stream,
                     idx, dwA, pwA, gwA, dwB, gwB, Wball);

  for (int node = 1; node <= 6; node++){
    hipLaunchKernelGGL(k_gemm_pool, dim3(512), dim3(512), 0, stream,
                       node, xb, Wball, tmp, idx);
    hipLaunchKernelGGL(k_stats_node, dim3(128), dim3(512), 0, stream,
                       node, tmp, sb[0], sb[1], sb[2], sb[3], sb[4], part, idx);
    hipLaunchKernelGGL(k_stats2_node, dim3(1), dim3(512), 0, stream,
                       node, part, alphaAll, mvalAll, idx);
    hipLaunchKernelGGL(k_fused, dim3(512), dim3(512), 0, stream,
                       node, xb, sb[0], sb[1], sb[2], sb[3], sb[4],
                       (node < 6) ? sb[node-1] : sb[0], out,
                       tmp, Wball, dbA, gbA, dbB, gbB,
                       alphaAll, mvalAll, idx, wsc);
  }
}